// Round 1
// baseline (242.382 us; speedup 1.0000x reference)
//
#include <hip/hip_runtime.h>

#define H_TOKN 57
#define OUT_HW 800
#define NMASK 64
#define C_IN 768
#define C8N 96
#define L_OUT 21
#define NPIX 3249          // 57*57
#define M_TOT 6498         // 2*3249
#define YSTR 24            // padded channel stride for y57
#define SCALE (57.0f/800.0f)

// ---------- Kernel A1: h[P][96] = relu(e[P][768] @ w1[96][768]^T + b1) ----------
__global__ __launch_bounds__(256) void conv1_kernel(
    const float* __restrict__ e, const float* __restrict__ w1,
    const float* __restrict__ b1, float* __restrict__ h)
{
  __shared__ float e_lds[32][36];
  __shared__ float w_lds[96][36];
  const int tid = threadIdx.x;
  const int m0 = blockIdx.x * 32;
  const int tx = tid & 15;   // pixel pair index
  const int ty = tid >> 4;   // c8 group of 6
  float acc[2][6] = {};
  const int srow = tid >> 3;
  const int skoff = (tid & 7) << 2;
  for (int k0 = 0; k0 < C_IN; k0 += 32) {
    {
      int p = m0 + srow; if (p >= M_TOT) p = M_TOT - 1;
      float4 v = *(const float4*)(e + (size_t)p * C_IN + k0 + skoff);
      *(float4*)&e_lds[srow][skoff] = v;
    }
    #pragma unroll
    for (int pass = 0; pass < 3; ++pass) {
      int row = srow + pass * 32;
      float4 v = *(const float4*)(w1 + (size_t)row * C_IN + k0 + skoff);
      *(float4*)&w_lds[row][skoff] = v;
    }
    __syncthreads();
    #pragma unroll
    for (int k4 = 0; k4 < 32; k4 += 4) {
      float4 e0 = *(const float4*)&e_lds[2*tx+0][k4];
      float4 e1 = *(const float4*)&e_lds[2*tx+1][k4];
      #pragma unroll
      for (int cc = 0; cc < 6; ++cc) {
        float4 wv = *(const float4*)&w_lds[ty*6+cc][k4];
        acc[0][cc] += e0.x*wv.x + e0.y*wv.y + e0.z*wv.z + e0.w*wv.w;
        acc[1][cc] += e1.x*wv.x + e1.y*wv.y + e1.z*wv.z + e1.w*wv.w;
      }
    }
    __syncthreads();
  }
  #pragma unroll
  for (int pp = 0; pp < 2; ++pp) {
    int p = m0 + 2*tx + pp;
    if (p < M_TOT) {
      #pragma unroll
      for (int cc = 0; cc < 6; ++cc) {
        int c = ty*6 + cc;
        h[(size_t)p*C8N + c] = fmaxf(acc[pp][cc] + b1[c], 0.f);
      }
    }
  }
}

// ---------- Kernel A2: y57[P][24] = h[P][96] @ w2[21][96]^T  (pads 21..23 = 0) ----------
__global__ __launch_bounds__(256) void conv2_kernel(
    const float* __restrict__ h, const float* __restrict__ w2,
    float* __restrict__ y57)
{
  __shared__ float h_lds[64][97];
  __shared__ float w2_lds[L_OUT*C8N];
  const int tid = threadIdx.x;
  const int p0 = blockIdx.x * 64;
  for (int i = tid; i < L_OUT*C8N; i += 256) w2_lds[i] = w2[i];
  for (int i = tid; i < 64*C8N; i += 256) {
    int r = i / C8N, c = i - r * C8N;
    int p = p0 + r; if (p >= M_TOT) p = M_TOT - 1;
    h_lds[r][c] = h[(size_t)p*C8N + c];
  }
  __syncthreads();
  const int tx = tid & 63, ty = tid >> 6;  // ty uniform per wave
  float acc[6] = {0.f,0.f,0.f,0.f,0.f,0.f};
  for (int c = 0; c < C8N; ++c) {
    float hv = h_lds[tx][c];
    #pragma unroll
    for (int k = 0; k < 5; ++k)
      acc[k] += hv * w2_lds[(ty + 4*k)*C8N + c];
    if (ty == 0) acc[5] += hv * w2_lds[20*C8N + c];
  }
  int p = p0 + tx;
  if (p < M_TOT) {
    float* yr = y57 + (size_t)p * YSTR;
    #pragma unroll
    for (int k = 0; k < 5; ++k) yr[ty + 4*k] = acc[k];
    yr[ty + 20] = (ty == 0) ? acc[5] : 0.f;  // ty=0 writes l=20; ty=1..3 zero the pads
  }
}

// ---------- Kernel B: segment sums/counts over bilinear-upsampled y ----------
__global__ __launch_bounds__(256) void segsum_kernel(
    const float* __restrict__ y57, const int* __restrict__ labels,
    float* __restrict__ sums, float* __restrict__ counts, int chunk)
{
  __shared__ float s_sum[NMASK*25];  // stride 25: coprime-ish bank spread
  __shared__ float s_cnt[NMASK];
  const int tid = threadIdx.x;
  const int b = blockIdx.y;
  for (int i = tid; i < NMASK*25; i += 256) s_sum[i] = 0.f;
  if (tid < NMASK) s_cnt[tid] = 0.f;
  __syncthreads();
  const float* yb = y57 + (size_t)b * NPIX * YSTR;
  const int* lb = labels + (size_t)b * OUT_HW * OUT_HW;
  const int start = blockIdx.x * chunk;
  for (int i = tid; i < chunk; i += 256) {
    int p = start + i;
    int hh = p / OUT_HW;
    int ww = p - hh * OUT_HW;
    float th = (hh + 0.5f) * SCALE - 0.5f;
    th = fminf(fmaxf(th, 0.f), 56.f);
    int i0 = min((int)th, 55);
    float fh = th - (float)i0;
    float tw = (ww + 0.5f) * SCALE - 0.5f;
    tw = fminf(fmaxf(tw, 0.f), 56.f);
    int j0 = min((int)tw, 55);
    float fw = tw - (float)j0;
    int m = lb[p] & (NMASK-1);
    float w00 = (1.f-fh)*(1.f-fw), w01 = (1.f-fh)*fw;
    float w10 = fh*(1.f-fw), w11 = fh*fw;
    const float4* t00 = (const float4*)(yb + ((size_t)i0*H_TOKN + j0) * YSTR);
    const float4* t01 = t00 + 6;
    const float4* t10 = (const float4*)(yb + ((size_t)(i0+1)*H_TOKN + j0) * YSTR);
    const float4* t11 = t10 + 6;
    float* sm = s_sum + m * 25;
    atomicAdd(&s_cnt[m], 1.f);
    #pragma unroll
    for (int c = 0; c < 5; ++c) {
      float4 a = t00[c], bb = t01[c], cc = t10[c], d = t11[c];
      atomicAdd(&sm[c*4+0], w00*a.x + w01*bb.x + w10*cc.x + w11*d.x);
      atomicAdd(&sm[c*4+1], w00*a.y + w01*bb.y + w10*cc.y + w11*d.y);
      atomicAdd(&sm[c*4+2], w00*a.z + w01*bb.z + w10*cc.z + w11*d.z);
      atomicAdd(&sm[c*4+3], w00*a.w + w01*bb.w + w10*cc.w + w11*d.w);
    }
    {
      const float* f00 = (const float*)t00; const float* f01 = (const float*)t01;
      const float* f10 = (const float*)t10; const float* f11 = (const float*)t11;
      atomicAdd(&sm[20], w00*f00[20] + w01*f01[20] + w10*f10[20] + w11*f11[20]);
    }
  }
  __syncthreads();
  float* sb = sums + (size_t)b * NMASK * YSTR;
  for (int i = tid; i < NMASK * YSTR; i += 256) {
    int m = i / YSTR, l = i - m * YSTR;
    if (l < L_OUT) atomicAdd(&sb[i], s_sum[m*25 + l]);
  }
  if (tid < NMASK) atomicAdd(&counts[b*NMASK + tid], s_cnt[tid]);
}

// ---------- Kernel C: out[b][l][h][w] = bilinear(y57)[l] + mean[label][l] + b2[l] ----------
__global__ __launch_bounds__(256) void final_kernel(
    const float* __restrict__ y57, const int* __restrict__ labels,
    const float* __restrict__ sums, const float* __restrict__ counts,
    const float* __restrict__ b2, float* __restrict__ out)
{
  __shared__ __align__(16) float row0[H_TOKN*YSTR];
  __shared__ __align__(16) float row1[H_TOKN*YSTR];
  __shared__ __align__(16) float meanL[NMASK*28];  // stride 28 (=16B aligned, 7m+c bank spread)
  const int tid = threadIdx.x;
  const int hh = blockIdx.y;
  const int b = blockIdx.z;
  float th = (hh + 0.5f) * SCALE - 0.5f;
  th = fminf(fmaxf(th, 0.f), 56.f);
  int i0 = min((int)th, 55);
  float fh = th - (float)i0;
  const float* yb = y57 + (size_t)b * NPIX * YSTR;
  const float* r0 = yb + (size_t)i0 * H_TOKN * YSTR;
  const float* r1 = r0 + H_TOKN * YSTR;
  for (int i = tid; i < H_TOKN*YSTR; i += 256) { row0[i] = r0[i]; row1[i] = r1[i]; }
  for (int i = tid; i < NMASK*YSTR; i += 256) {
    int m = i / YSTR, l = i - m * YSTR;
    meanL[m*28 + l] = sums[(size_t)b*NMASK*YSTR + i] / fmaxf(counts[b*NMASK + m], 1.f);
  }
  __syncthreads();
  float bias[L_OUT];
  #pragma unroll
  for (int l = 0; l < L_OUT; ++l) bias[l] = b2[l];
  const int* lrow = labels + ((size_t)b * OUT_HW + hh) * OUT_HW;
  float* ob = out + (size_t)b * L_OUT * OUT_HW * OUT_HW + (size_t)hh * OUT_HW;
  const float ifh = 1.f - fh;
  for (int w = tid; w < OUT_HW; w += 256) {
    float tw = (w + 0.5f) * SCALE - 0.5f;
    tw = fminf(fmaxf(tw, 0.f), 56.f);
    int j0 = min((int)tw, 55);
    float fw = tw - (float)j0;
    int m = lrow[w] & (NMASK-1);
    float w00 = ifh*(1.f-fw), w01 = ifh*fw, w10 = fh*(1.f-fw), w11 = fh*fw;
    const float4* a0 = (const float4*)&row0[j0*YSTR];
    const float4* a1 = a0 + 6;
    const float4* c0 = (const float4*)&row1[j0*YSTR];
    const float4* c1 = c0 + 6;
    const float4* mv = (const float4*)&meanL[m*28];
    #pragma unroll
    for (int c = 0; c < 6; ++c) {
      float4 A = a0[c], B = a1[c], Cc = c0[c], D = c1[c], Mv = mv[c];
      float v0 = w00*A.x + w01*B.x + w10*Cc.x + w11*D.x + Mv.x;
      float v1 = w00*A.y + w01*B.y + w10*Cc.y + w11*D.y + Mv.y;
      float v2 = w00*A.z + w01*B.z + w10*Cc.z + w11*D.z + Mv.z;
      float v3 = w00*A.w + w01*B.w + w10*Cc.w + w11*D.w + Mv.w;
      const int lb_ = c*4;
      ob[(size_t)(lb_+0)*640000 + w] = v0 + bias[lb_+0];
      if (lb_+1 < L_OUT) ob[(size_t)(lb_+1)*640000 + w] = v1 + bias[lb_+1];
      if (lb_+2 < L_OUT) ob[(size_t)(lb_+2)*640000 + w] = v2 + bias[lb_+2];
      if (lb_+3 < L_OUT) ob[(size_t)(lb_+3)*640000 + w] = v3 + bias[lb_+3];
    }
  }
}

extern "C" void kernel_launch(void* const* d_in, const int* in_sizes, int n_in,
                              void* d_out, int out_size, void* d_ws, size_t ws_size,
                              hipStream_t stream)
{
  const float* e   = (const float*)d_in[0];
  const int*   lab = (const int*)d_in[1];
  const float* w1  = (const float*)d_in[2];
  const float* b1  = (const float*)d_in[3];
  const float* w2  = (const float*)d_in[4];
  const float* b2  = (const float*)d_in[5];
  float* out = (float*)d_out;
  float* ws  = (float*)d_ws;

  float* h_ws   = ws;                                   // 6498*96 f32
  float* y57_ws = h_ws + (size_t)M_TOT * C8N;           // 6498*24 f32
  float* sums   = y57_ws + (size_t)M_TOT * YSTR;        // 2*64*24 f32
  float* cnts   = sums + 2*NMASK*YSTR;                  // 2*64 f32

  // zero the atomic accumulators (sums + counts are contiguous)
  hipMemsetAsync(sums, 0, (size_t)(2*NMASK*YSTR + 2*NMASK) * sizeof(float), stream);

  conv1_kernel<<<dim3((M_TOT + 31)/32), 256, 0, stream>>>(e, w1, b1, h_ws);
  conv2_kernel<<<dim3((M_TOT + 63)/64), 256, 0, stream>>>(h_ws, w2, y57_ws);
  {
    const int nb = 256;                       // blocks per batch
    const int chunk = (OUT_HW*OUT_HW) / nb;   // 2500, exact
    segsum_kernel<<<dim3(nb, 2), 256, 0, stream>>>(y57_ws, lab, sums, cnts, chunk);
  }
  final_kernel<<<dim3(1, OUT_HW, 2), 256, 0, stream>>>(y57_ws, lab, sums, cnts, b2, out);
}

// Round 2
// 138.175 us; speedup vs baseline: 1.7542x; 1.7542x over previous
//
#include <hip/hip_runtime.h>

#define H_TOKN 57
#define OUT_HW 800
#define NMASK 64
#define C_IN 768
#define C8N 96
#define L_OUT 21
#define NPIX 3249          // 57*57
#define M_TOT 6498         // 2*3249
#define YSTR 24            // padded channel stride for y57
#define SCALE (57.0f/800.0f)

#define ROWS_PB 25
#define COLS_PB 100
#define ROWS_T 4
#define COLS_T 10
#define MSTRIDE 41         // 40 used per mask; 41 -> (9m+c)%32 spreads banks

// ---------- Kernel A1: h[P][96] = relu(e[P][768] @ w1[96][768]^T + b1) ----------
__global__ __launch_bounds__(256) void conv1_kernel(
    const float* __restrict__ e, const float* __restrict__ w1,
    const float* __restrict__ b1, float* __restrict__ h)
{
  __shared__ float e_lds[32][36];
  __shared__ float w_lds[96][36];
  const int tid = threadIdx.x;
  const int m0 = blockIdx.x * 32;
  const int tx = tid & 15;   // pixel pair index
  const int ty = tid >> 4;   // c8 group of 6
  float acc[2][6] = {};
  const int srow = tid >> 3;
  const int skoff = (tid & 7) << 2;
  for (int k0 = 0; k0 < C_IN; k0 += 32) {
    {
      int p = m0 + srow; if (p >= M_TOT) p = M_TOT - 1;
      float4 v = *(const float4*)(e + (size_t)p * C_IN + k0 + skoff);
      *(float4*)&e_lds[srow][skoff] = v;
    }
    #pragma unroll
    for (int pass = 0; pass < 3; ++pass) {
      int row = srow + pass * 32;
      float4 v = *(const float4*)(w1 + (size_t)row * C_IN + k0 + skoff);
      *(float4*)&w_lds[row][skoff] = v;
    }
    __syncthreads();
    #pragma unroll
    for (int k4 = 0; k4 < 32; k4 += 4) {
      float4 e0 = *(const float4*)&e_lds[2*tx+0][k4];
      float4 e1 = *(const float4*)&e_lds[2*tx+1][k4];
      #pragma unroll
      for (int cc = 0; cc < 6; ++cc) {
        float4 wv = *(const float4*)&w_lds[ty*6+cc][k4];
        acc[0][cc] += e0.x*wv.x + e0.y*wv.y + e0.z*wv.z + e0.w*wv.w;
        acc[1][cc] += e1.x*wv.x + e1.y*wv.y + e1.z*wv.z + e1.w*wv.w;
      }
    }
    __syncthreads();
  }
  #pragma unroll
  for (int pp = 0; pp < 2; ++pp) {
    int p = m0 + 2*tx + pp;
    if (p < M_TOT) {
      #pragma unroll
      for (int cc = 0; cc < 6; ++cc) {
        int c = ty*6 + cc;
        h[(size_t)p*C8N + c] = fmaxf(acc[pp][cc] + b1[c], 0.f);
      }
    }
  }
}

// ---------- Kernel A2: y57[P][24] = h[P][96] @ w2[21][96]^T  (pads 21..23 = 0) ----------
__global__ __launch_bounds__(256) void conv2_kernel(
    const float* __restrict__ h, const float* __restrict__ w2,
    float* __restrict__ y57)
{
  __shared__ float h_lds[64][97];
  __shared__ float w2_lds[L_OUT*C8N];
  const int tid = threadIdx.x;
  const int p0 = blockIdx.x * 64;
  for (int i = tid; i < L_OUT*C8N; i += 256) w2_lds[i] = w2[i];
  for (int i = tid; i < 64*C8N; i += 256) {
    int r = i / C8N, c = i - r * C8N;
    int p = p0 + r; if (p >= M_TOT) p = M_TOT - 1;
    h_lds[r][c] = h[(size_t)p*C8N + c];
  }
  __syncthreads();
  const int tx = tid & 63, ty = tid >> 6;  // ty uniform per wave
  float acc[6] = {0.f,0.f,0.f,0.f,0.f,0.f};
  for (int c = 0; c < C8N; ++c) {
    float hv = h_lds[tx][c];
    #pragma unroll
    for (int k = 0; k < 5; ++k)
      acc[k] += hv * w2_lds[(ty + 4*k)*C8N + c];
    if (ty == 0) acc[5] += hv * w2_lds[20*C8N + c];
  }
  int p = p0 + tx;
  if (p < M_TOT) {
    float* yr = y57 + (size_t)p * YSTR;
    #pragma unroll
    for (int k = 0; k < 5; ++k) yr[ty + 4*k] = acc[k];
    yr[ty + 20] = (ty == 0) ? acc[5] : 0.f;  // ty=0 writes l=20; ty=1..3 zero the pads
  }
}

// ---------- Kernel B1: bin bilinear weights per (mask, tap) -> W[b][64][3249] ----------
// W depends ONLY on labels (bilinear is linear in taps). 4 LDS atomics/pixel.
__global__ __launch_bounds__(256) void binweights_kernel(
    const int* __restrict__ labels, float* __restrict__ W)
{
  __shared__ float s_w[NMASK * MSTRIDE];
  const int tid = threadIdx.x;
  const int wc0 = blockIdx.x * COLS_PB;
  const int hr0 = blockIdx.y * ROWS_PB;
  const int b = blockIdx.z;
  for (int i = tid; i < NMASK*MSTRIDE; i += 256) s_w[i] = 0.f;
  __syncthreads();
  // tap bases for this block (monotone: offsets fit in ROWS_T x COLS_T)
  float thb = fminf(fmaxf((hr0 + 0.5f) * SCALE - 0.5f, 0.f), 56.f);
  const int ib = min((int)thb, 55);
  float twb = fminf(fmaxf((wc0 + 0.5f) * SCALE - 0.5f, 0.f), 56.f);
  const int jb = min((int)twb, 55);
  const int* lb = labels + (size_t)b * OUT_HW * OUT_HW;
  for (int i = tid; i < ROWS_PB*COLS_PB; i += 256) {
    int dh = i / COLS_PB;
    int dw = i - dh * COLS_PB;
    int hh = hr0 + dh, ww = wc0 + dw;
    float th = fminf(fmaxf((hh + 0.5f) * SCALE - 0.5f, 0.f), 56.f);
    int i0 = min((int)th, 55);
    float fh = th - (float)i0;
    float tw = fminf(fmaxf((ww + 0.5f) * SCALE - 0.5f, 0.f), 56.f);
    int j0 = min((int)tw, 55);
    float fw = tw - (float)j0;
    int m = lb[(size_t)hh * OUT_HW + ww] & (NMASK-1);
    float* sm = s_w + m * MSTRIDE + (i0 - ib) * COLS_T + (j0 - jb);
    float w11 = fh * fw;
    float w10 = fh - w11;
    float w01 = fw - w11;
    float w00 = 1.f - fh - fw + w11;
    unsafeAtomicAdd(sm, w00);
    unsafeAtomicAdd(sm + 1, w01);
    unsafeAtomicAdd(sm + COLS_T, w10);
    unsafeAtomicAdd(sm + COLS_T + 1, w11);
  }
  __syncthreads();
  float* Wb = W + (size_t)b * NMASK * NPIX;
  for (int i = tid; i < NMASK * ROWS_T * COLS_T; i += 256) {
    int m = i / (ROWS_T*COLS_T);
    int r = i - m * (ROWS_T*COLS_T);
    int li = r / COLS_T, lj = r - li * COLS_T;
    float v = s_w[m*MSTRIDE + r];
    int I = ib + li, J = jb + lj;
    if (v != 0.f && I <= 56 && J <= 56)
      unsafeAtomicAdd(&Wb[(size_t)m * NPIX + I*H_TOKN + J], v);
  }
}

// ---------- Kernel B2: sums[b][m][:] = W[b][m][:] @ y57[b];  counts = sum(W) ----------
__global__ __launch_bounds__(256) void segreduce_kernel(
    const float* __restrict__ W, const float* __restrict__ y57,
    float* __restrict__ sums, float* __restrict__ counts)
{
  const int bm = blockIdx.x;           // b*64 + m
  const int b = bm >> 6;
  const int tid = threadIdx.x;
  const float* wr = W + (size_t)bm * NPIX;
  const float* yb = y57 + (size_t)b * NPIX * YSTR;
  float acc[24] = {};
  float cnt = 0.f;
  for (int t = tid; t < NPIX; t += 256) {
    float wv = wr[t];
    if (wv != 0.f) {
      cnt += wv;
      const float* y = yb + (size_t)t * YSTR;
      #pragma unroll
      for (int l = 0; l < 24; l += 4) {
        float4 v = *(const float4*)(y + l);
        acc[l+0] += wv*v.x; acc[l+1] += wv*v.y;
        acc[l+2] += wv*v.z; acc[l+3] += wv*v.w;
      }
    }
  }
  #pragma unroll
  for (int off = 32; off > 0; off >>= 1) {
    #pragma unroll
    for (int l = 0; l < 24; ++l) acc[l] += __shfl_down(acc[l], off, 64);
    cnt += __shfl_down(cnt, off, 64);
  }
  __shared__ float s_red[4][28];
  const int wid = tid >> 6, lane = tid & 63;
  if (lane == 0) {
    #pragma unroll
    for (int l = 0; l < 24; ++l) s_red[wid][l] = acc[l];
    s_red[wid][24] = cnt;
  }
  __syncthreads();
  if (tid < 25) {
    float v = s_red[0][tid] + s_red[1][tid] + s_red[2][tid] + s_red[3][tid];
    if (tid < 24) sums[(size_t)bm * YSTR + tid] = v;
    else counts[bm] = v;
  }
}

// ---------- Kernel C: out[b][l][h][w] = bilinear(y57)[l] + mean[label][l] + b2[l] ----------
__global__ __launch_bounds__(256) void final_kernel(
    const float* __restrict__ y57, const int* __restrict__ labels,
    const float* __restrict__ sums, const float* __restrict__ counts,
    const float* __restrict__ b2, float* __restrict__ out)
{
  __shared__ __align__(16) float row0[H_TOKN*YSTR];
  __shared__ __align__(16) float row1[H_TOKN*YSTR];
  __shared__ __align__(16) float meanL[NMASK*28];
  const int tid = threadIdx.x;
  const int hh = blockIdx.y;
  const int b = blockIdx.z;
  float th = (hh + 0.5f) * SCALE - 0.5f;
  th = fminf(fmaxf(th, 0.f), 56.f);
  int i0 = min((int)th, 55);
  float fh = th - (float)i0;
  const float* yb = y57 + (size_t)b * NPIX * YSTR;
  const float* r0 = yb + (size_t)i0 * H_TOKN * YSTR;
  const float* r1 = r0 + H_TOKN * YSTR;
  for (int i = tid; i < H_TOKN*YSTR; i += 256) { row0[i] = r0[i]; row1[i] = r1[i]; }
  for (int i = tid; i < NMASK*YSTR; i += 256) {
    int m = i / YSTR, l = i - m * YSTR;
    meanL[m*28 + l] = sums[(size_t)b*NMASK*YSTR + i] / fmaxf(counts[b*NMASK + m], 1.f);
  }
  __syncthreads();
  float bias[L_OUT];
  #pragma unroll
  for (int l = 0; l < L_OUT; ++l) bias[l] = b2[l];
  const int* lrow = labels + ((size_t)b * OUT_HW + hh) * OUT_HW;
  float* ob = out + (size_t)b * L_OUT * OUT_HW * OUT_HW + (size_t)hh * OUT_HW;
  const float ifh = 1.f - fh;
  for (int w = tid; w < OUT_HW; w += 256) {
    float tw = (w + 0.5f) * SCALE - 0.5f;
    tw = fminf(fmaxf(tw, 0.f), 56.f);
    int j0 = min((int)tw, 55);
    float fw = tw - (float)j0;
    int m = lrow[w] & (NMASK-1);
    float w00 = ifh*(1.f-fw), w01 = ifh*fw, w10 = fh*(1.f-fw), w11 = fh*fw;
    const float4* a0 = (const float4*)&row0[j0*YSTR];
    const float4* a1 = a0 + 6;
    const float4* c0 = (const float4*)&row1[j0*YSTR];
    const float4* c1 = c0 + 6;
    const float4* mv = (const float4*)&meanL[m*28];
    #pragma unroll
    for (int c = 0; c < 6; ++c) {
      float4 A = a0[c], B = a1[c], Cc = c0[c], D = c1[c], Mv = mv[c];
      float v0 = w00*A.x + w01*B.x + w10*Cc.x + w11*D.x + Mv.x;
      float v1 = w00*A.y + w01*B.y + w10*Cc.y + w11*D.y + Mv.y;
      float v2 = w00*A.z + w01*B.z + w10*Cc.z + w11*D.z + Mv.z;
      float v3 = w00*A.w + w01*B.w + w10*Cc.w + w11*D.w + Mv.w;
      const int lb_ = c*4;
      ob[(size_t)(lb_+0)*640000 + w] = v0 + bias[lb_+0];
      if (lb_+1 < L_OUT) ob[(size_t)(lb_+1)*640000 + w] = v1 + bias[lb_+1];
      if (lb_+2 < L_OUT) ob[(size_t)(lb_+2)*640000 + w] = v2 + bias[lb_+2];
      if (lb_+3 < L_OUT) ob[(size_t)(lb_+3)*640000 + w] = v3 + bias[lb_+3];
    }
  }
}

extern "C" void kernel_launch(void* const* d_in, const int* in_sizes, int n_in,
                              void* d_out, int out_size, void* d_ws, size_t ws_size,
                              hipStream_t stream)
{
  const float* e   = (const float*)d_in[0];
  const int*   lab = (const int*)d_in[1];
  const float* w1  = (const float*)d_in[2];
  const float* b1  = (const float*)d_in[3];
  const float* w2  = (const float*)d_in[4];
  const float* b2  = (const float*)d_in[5];
  float* out = (float*)d_out;
  float* ws  = (float*)d_ws;

  float* h_ws   = ws;                                   // 6498*96 f32
  float* y57_ws = h_ws + (size_t)M_TOT * C8N;           // 6498*24 f32
  float* W_ws   = y57_ws + (size_t)M_TOT * YSTR;        // 2*64*3249 f32
  float* sums   = W_ws + (size_t)2 * NMASK * NPIX;      // 2*64*24 f32
  float* cnts   = sums + 2*NMASK*YSTR;                  // 2*64 f32

  // zero only the W accumulator (atomics); sums/counts are overwritten
  hipMemsetAsync(W_ws, 0, (size_t)2 * NMASK * NPIX * sizeof(float), stream);

  conv1_kernel<<<dim3((M_TOT + 31)/32), 256, 0, stream>>>(e, w1, b1, h_ws);
  conv2_kernel<<<dim3((M_TOT + 63)/64), 256, 0, stream>>>(h_ws, w2, y57_ws);
  binweights_kernel<<<dim3(OUT_HW/COLS_PB, OUT_HW/ROWS_PB, 2), 256, 0, stream>>>(lab, W_ws);
  segreduce_kernel<<<dim3(2*NMASK), 256, 0, stream>>>(W_ws, y57_ws, sums, cnts);
  final_kernel<<<dim3(1, OUT_HW, 2), 256, 0, stream>>>(y57_ws, lab, sums, cnts, b2, out);
}

// Round 3
// 136.970 us; speedup vs baseline: 1.7696x; 1.0088x over previous
//
#include <hip/hip_runtime.h>

#define H_TOKN 57
#define OUT_HW 800
#define NMASK 64
#define C_IN 768
#define C8N 96
#define L_OUT 21
#define NPIX 3249          // 57*57
#define M_TOT 6498         // 2*3249
#define YSTR 24            // padded channel stride for y57
#define SCALE (57.0f/800.0f)

#define ROWS_PB 25
#define COLS_PB 100
#define ROWS_T 4
#define COLS_T 10
#define MSTRIDE 41         // 40 used per mask; 41 -> (9m+c)%32 spreads banks

#define W_ELEMS (2 * NMASK * NPIX)   // 415872, divisible by 4

// ---------- Kernel Z: zero the W accumulator (runtime fillBuffer was 62us!) ----------
__global__ __launch_bounds__(256) void zero_w_kernel(float* __restrict__ W)
{
  const int i = (blockIdx.x * 256 + threadIdx.x) * 4;
  if (i < W_ELEMS) *(float4*)(W + i) = make_float4(0.f, 0.f, 0.f, 0.f);
}

// ---------- Kernel A1: h[P][96] = relu(e[P][768] @ w1[96][768]^T + b1) ----------
__global__ __launch_bounds__(256) void conv1_kernel(
    const float* __restrict__ e, const float* __restrict__ w1,
    const float* __restrict__ b1, float* __restrict__ h)
{
  __shared__ float e_lds[32][36];
  __shared__ float w_lds[96][36];
  const int tid = threadIdx.x;
  const int m0 = blockIdx.x * 32;
  const int tx = tid & 15;   // pixel pair index
  const int ty = tid >> 4;   // c8 group of 6
  float acc[2][6] = {};
  const int srow = tid >> 3;
  const int skoff = (tid & 7) << 2;
  for (int k0 = 0; k0 < C_IN; k0 += 32) {
    {
      int p = m0 + srow; if (p >= M_TOT) p = M_TOT - 1;
      float4 v = *(const float4*)(e + (size_t)p * C_IN + k0 + skoff);
      *(float4*)&e_lds[srow][skoff] = v;
    }
    #pragma unroll
    for (int pass = 0; pass < 3; ++pass) {
      int row = srow + pass * 32;
      float4 v = *(const float4*)(w1 + (size_t)row * C_IN + k0 + skoff);
      *(float4*)&w_lds[row][skoff] = v;
    }
    __syncthreads();
    #pragma unroll
    for (int k4 = 0; k4 < 32; k4 += 4) {
      float4 e0 = *(const float4*)&e_lds[2*tx+0][k4];
      float4 e1 = *(const float4*)&e_lds[2*tx+1][k4];
      #pragma unroll
      for (int cc = 0; cc < 6; ++cc) {
        float4 wv = *(const float4*)&w_lds[ty*6+cc][k4];
        acc[0][cc] += e0.x*wv.x + e0.y*wv.y + e0.z*wv.z + e0.w*wv.w;
        acc[1][cc] += e1.x*wv.x + e1.y*wv.y + e1.z*wv.z + e1.w*wv.w;
      }
    }
    __syncthreads();
  }
  #pragma unroll
  for (int pp = 0; pp < 2; ++pp) {
    int p = m0 + 2*tx + pp;
    if (p < M_TOT) {
      #pragma unroll
      for (int cc = 0; cc < 6; ++cc) {
        int c = ty*6 + cc;
        h[(size_t)p*C8N + c] = fmaxf(acc[pp][cc] + b1[c], 0.f);
      }
    }
  }
}

// ---------- Kernel A2: y57[P][24] = h[P][96] @ w2[21][96]^T  (pads 21..23 = 0) ----------
__global__ __launch_bounds__(256) void conv2_kernel(
    const float* __restrict__ h, const float* __restrict__ w2,
    float* __restrict__ y57)
{
  __shared__ float h_lds[64][97];
  __shared__ float w2_lds[L_OUT*C8N];
  const int tid = threadIdx.x;
  const int p0 = blockIdx.x * 64;
  for (int i = tid; i < L_OUT*C8N; i += 256) w2_lds[i] = w2[i];
  for (int i = tid; i < 64*C8N; i += 256) {
    int r = i / C8N, c = i - r * C8N;
    int p = p0 + r; if (p >= M_TOT) p = M_TOT - 1;
    h_lds[r][c] = h[(size_t)p*C8N + c];
  }
  __syncthreads();
  const int tx = tid & 63, ty = tid >> 6;  // ty uniform per wave
  float acc[6] = {0.f,0.f,0.f,0.f,0.f,0.f};
  for (int c = 0; c < C8N; ++c) {
    float hv = h_lds[tx][c];
    #pragma unroll
    for (int k = 0; k < 5; ++k)
      acc[k] += hv * w2_lds[(ty + 4*k)*C8N + c];
    if (ty == 0) acc[5] += hv * w2_lds[20*C8N + c];
  }
  int p = p0 + tx;
  if (p < M_TOT) {
    float* yr = y57 + (size_t)p * YSTR;
    #pragma unroll
    for (int k = 0; k < 5; ++k) yr[ty + 4*k] = acc[k];
    yr[ty + 20] = (ty == 0) ? acc[5] : 0.f;  // ty=0 writes l=20; ty=1..3 zero the pads
  }
}

// ---------- Kernel B1: bin bilinear weights per (mask, tap) -> W[b][64][3249] ----------
__global__ __launch_bounds__(256) void binweights_kernel(
    const int* __restrict__ labels, float* __restrict__ W)
{
  __shared__ float s_w[NMASK * MSTRIDE];
  const int tid = threadIdx.x;
  const int wc0 = blockIdx.x * COLS_PB;
  const int hr0 = blockIdx.y * ROWS_PB;
  const int b = blockIdx.z;
  for (int i = tid; i < NMASK*MSTRIDE; i += 256) s_w[i] = 0.f;
  __syncthreads();
  float thb = fminf(fmaxf((hr0 + 0.5f) * SCALE - 0.5f, 0.f), 56.f);
  const int ib = min((int)thb, 55);
  float twb = fminf(fmaxf((wc0 + 0.5f) * SCALE - 0.5f, 0.f), 56.f);
  const int jb = min((int)twb, 55);
  const int* lb = labels + (size_t)b * OUT_HW * OUT_HW;
  for (int i = tid; i < ROWS_PB*COLS_PB; i += 256) {
    int dh = i / COLS_PB;
    int dw = i - dh * COLS_PB;
    int hh = hr0 + dh, ww = wc0 + dw;
    float th = fminf(fmaxf((hh + 0.5f) * SCALE - 0.5f, 0.f), 56.f);
    int i0 = min((int)th, 55);
    float fh = th - (float)i0;
    float tw = fminf(fmaxf((ww + 0.5f) * SCALE - 0.5f, 0.f), 56.f);
    int j0 = min((int)tw, 55);
    float fw = tw - (float)j0;
    int m = lb[(size_t)hh * OUT_HW + ww] & (NMASK-1);
    float* sm = s_w + m * MSTRIDE + (i0 - ib) * COLS_T + (j0 - jb);
    float w11 = fh * fw;
    float w10 = fh - w11;
    float w01 = fw - w11;
    float w00 = 1.f - fh - fw + w11;
    unsafeAtomicAdd(sm, w00);
    unsafeAtomicAdd(sm + 1, w01);
    unsafeAtomicAdd(sm + COLS_T, w10);
    unsafeAtomicAdd(sm + COLS_T + 1, w11);
  }
  __syncthreads();
  float* Wb = W + (size_t)b * NMASK * NPIX;
  for (int i = tid; i < NMASK * ROWS_T * COLS_T; i += 256) {
    int m = i / (ROWS_T*COLS_T);
    int r = i - m * (ROWS_T*COLS_T);
    int li = r / COLS_T, lj = r - li * COLS_T;
    float v = s_w[m*MSTRIDE + r];
    int I = ib + li, J = jb + lj;
    if (v != 0.f && I <= 56 && J <= 56)
      unsafeAtomicAdd(&Wb[(size_t)m * NPIX + I*H_TOKN + J], v);
  }
}

// ---------- Kernel B2: sums[b][m][:] = W[b][m][:] @ y57[b];  counts = sum(W) ----------
__global__ __launch_bounds__(256) void segreduce_kernel(
    const float* __restrict__ W, const float* __restrict__ y57,
    float* __restrict__ sums, float* __restrict__ counts)
{
  const int bm = blockIdx.x;           // b*64 + m
  const int b = bm >> 6;
  const int tid = threadIdx.x;
  const float* wr = W + (size_t)bm * NPIX;
  const float* yb = y57 + (size_t)b * NPIX * YSTR;
  float acc[24] = {};
  float cnt = 0.f;
  for (int t = tid; t < NPIX; t += 256) {
    float wv = wr[t];
    if (wv != 0.f) {
      cnt += wv;
      const float* y = yb + (size_t)t * YSTR;
      #pragma unroll
      for (int l = 0; l < 24; l += 4) {
        float4 v = *(const float4*)(y + l);
        acc[l+0] += wv*v.x; acc[l+1] += wv*v.y;
        acc[l+2] += wv*v.z; acc[l+3] += wv*v.w;
      }
    }
  }
  #pragma unroll
  for (int off = 32; off > 0; off >>= 1) {
    #pragma unroll
    for (int l = 0; l < 24; ++l) acc[l] += __shfl_down(acc[l], off, 64);
    cnt += __shfl_down(cnt, off, 64);
  }
  __shared__ float s_red[4][28];
  const int wid = tid >> 6, lane = tid & 63;
  if (lane == 0) {
    #pragma unroll
    for (int l = 0; l < 24; ++l) s_red[wid][l] = acc[l];
    s_red[wid][24] = cnt;
  }
  __syncthreads();
  if (tid < 25) {
    float v = s_red[0][tid] + s_red[1][tid] + s_red[2][tid] + s_red[3][tid];
    if (tid < 24) sums[(size_t)bm * YSTR + tid] = v;
    else counts[bm] = v;
  }
}

// ---------- Kernel C: out[b][l][h][w] = bilinear(y57)[l] + mean[label][l] + b2[l] ----------
__global__ __launch_bounds__(256) void final_kernel(
    const float* __restrict__ y57, const int* __restrict__ labels,
    const float* __restrict__ sums, const float* __restrict__ counts,
    const float* __restrict__ b2, float* __restrict__ out)
{
  __shared__ __align__(16) float row0[H_TOKN*YSTR];
  __shared__ __align__(16) float row1[H_TOKN*YSTR];
  __shared__ __align__(16) float meanL[NMASK*28];
  const int tid = threadIdx.x;
  const int hh = blockIdx.y;
  const int b = blockIdx.z;
  float th = (hh + 0.5f) * SCALE - 0.5f;
  th = fminf(fmaxf(th, 0.f), 56.f);
  int i0 = min((int)th, 55);
  float fh = th - (float)i0;
  const float* yb = y57 + (size_t)b * NPIX * YSTR;
  const float* r0 = yb + (size_t)i0 * H_TOKN * YSTR;
  const float* r1 = r0 + H_TOKN * YSTR;
  for (int i = tid; i < H_TOKN*YSTR; i += 256) { row0[i] = r0[i]; row1[i] = r1[i]; }
  for (int i = tid; i < NMASK*YSTR; i += 256) {
    int m = i / YSTR, l = i - m * YSTR;
    meanL[m*28 + l] = sums[(size_t)b*NMASK*YSTR + i] / fmaxf(counts[b*NMASK + m], 1.f);
  }
  __syncthreads();
  float bias[L_OUT];
  #pragma unroll
  for (int l = 0; l < L_OUT; ++l) bias[l] = b2[l];
  const int* lrow = labels + ((size_t)b * OUT_HW + hh) * OUT_HW;
  float* ob = out + (size_t)b * L_OUT * OUT_HW * OUT_HW + (size_t)hh * OUT_HW;
  const float ifh = 1.f - fh;
  for (int w = tid; w < OUT_HW; w += 256) {
    float tw = (w + 0.5f) * SCALE - 0.5f;
    tw = fminf(fmaxf(tw, 0.f), 56.f);
    int j0 = min((int)tw, 55);
    float fw = tw - (float)j0;
    int m = lrow[w] & (NMASK-1);
    float w00 = ifh*(1.f-fw), w01 = ifh*fw, w10 = fh*(1.f-fw), w11 = fh*fw;
    const float4* a0 = (const float4*)&row0[j0*YSTR];
    const float4* a1 = a0 + 6;
    const float4* c0 = (const float4*)&row1[j0*YSTR];
    const float4* c1 = c0 + 6;
    const float4* mv = (const float4*)&meanL[m*28];
    #pragma unroll
    for (int c = 0; c < 6; ++c) {
      float4 A = a0[c], B = a1[c], Cc = c0[c], D = c1[c], Mv = mv[c];
      float v0 = w00*A.x + w01*B.x + w10*Cc.x + w11*D.x + Mv.x;
      float v1 = w00*A.y + w01*B.y + w10*Cc.y + w11*D.y + Mv.y;
      float v2 = w00*A.z + w01*B.z + w10*Cc.z + w11*D.z + Mv.z;
      float v3 = w00*A.w + w01*B.w + w10*Cc.w + w11*D.w + Mv.w;
      const int lb_ = c*4;
      ob[(size_t)(lb_+0)*640000 + w] = v0 + bias[lb_+0];
      if (lb_+1 < L_OUT) ob[(size_t)(lb_+1)*640000 + w] = v1 + bias[lb_+1];
      if (lb_+2 < L_OUT) ob[(size_t)(lb_+2)*640000 + w] = v2 + bias[lb_+2];
      if (lb_+3 < L_OUT) ob[(size_t)(lb_+3)*640000 + w] = v3 + bias[lb_+3];
    }
  }
}

extern "C" void kernel_launch(void* const* d_in, const int* in_sizes, int n_in,
                              void* d_out, int out_size, void* d_ws, size_t ws_size,
                              hipStream_t stream)
{
  const float* e   = (const float*)d_in[0];
  const int*   lab = (const int*)d_in[1];
  const float* w1  = (const float*)d_in[2];
  const float* b1  = (const float*)d_in[3];
  const float* w2  = (const float*)d_in[4];
  const float* b2  = (const float*)d_in[5];
  float* out = (float*)d_out;
  float* ws  = (float*)d_ws;

  float* h_ws   = ws;                                   // 6498*96 f32
  float* y57_ws = h_ws + (size_t)M_TOT * C8N;           // 6498*24 f32
  float* W_ws   = y57_ws + (size_t)M_TOT * YSTR;        // 2*64*3249 f32
  float* sums   = W_ws + (size_t)W_ELEMS;               // 2*64*24 f32
  float* cnts   = sums + 2*NMASK*YSTR;                  // 2*64 f32

  zero_w_kernel<<<dim3((W_ELEMS/4 + 255)/256), 256, 0, stream>>>(W_ws);
  conv1_kernel<<<dim3((M_TOT + 31)/32), 256, 0, stream>>>(e, w1, b1, h_ws);
  conv2_kernel<<<dim3((M_TOT + 63)/64), 256, 0, stream>>>(h_ws, w2, y57_ws);
  binweights_kernel<<<dim3(OUT_HW/COLS_PB, OUT_HW/ROWS_PB, 2), 256, 0, stream>>>(lab, W_ws);
  segreduce_kernel<<<dim3(2*NMASK), 256, 0, stream>>>(W_ws, y57_ws, sums, cnts);
  final_kernel<<<dim3(1, OUT_HW, 2), 256, 0, stream>>>(y57_ws, lab, sums, cnts, b2, out);
}

// Round 4
// 104.457 us; speedup vs baseline: 2.3204x; 1.3113x over previous
//
#include <hip/hip_runtime.h>

#define H_TOKN 57
#define OUT_HW 800
#define NMASK 64
#define C_IN 768
#define C8N 96
#define L_OUT 21
#define NPIX 3249          // 57*57
#define M_TOT 6498         // 2*3249
#define YSTR 24            // padded channel stride for y57
#define SCALE (57.0f/800.0f)

#define ROWS_PB 25
#define COLS_PB 100
#define ROWS_T 4
#define COLS_T 10
#define MSTRIDE 41

#define W_ELEMS (2 * NMASK * NPIX)   // 415872, divisible by 4

#define BM 64
#define BK 32
#define ESTR 40            // bf16 LDS row stride (80B: 16 rows -> 2-way max, free)
#define HSTR 97            // f32 LDS row stride (odd -> conflict-free column reads)

// ---------- Kernel Z: zero the W accumulator ----------
__global__ __launch_bounds__(256) void zero_w_kernel(float* __restrict__ W)
{
  const int i = (blockIdx.x * 256 + threadIdx.x) * 4;
  if (i < W_ELEMS) *(float4*)(W + i) = make_float4(0.f, 0.f, 0.f, 0.f);
}

static __device__ __forceinline__ unsigned short f2bf(float f) {
  unsigned u = __float_as_uint(f);
  u += 0x7FFFu + ((u >> 16) & 1u);   // RTNE
  return (unsigned short)(u >> 16);
}

// ---------- Kernel A (fused): y57 = pad21_24( relu(e@w1^T + b1) @ w2^T ) ----------
// conv1 via bf16 MFMA (f32 accumulate), conv2 fused in epilogue from LDS.
__global__ __launch_bounds__(256) void fused_conv_kernel(
    const float* __restrict__ e, const float* __restrict__ w1,
    const float* __restrict__ b1, const float* __restrict__ w2,
    float* __restrict__ y57)
{
  using bf16x8 = __attribute__((ext_vector_type(8))) short;
  using f32x4  = __attribute__((ext_vector_type(4))) float;
  __shared__ __align__(16) unsigned short eA[BM * ESTR];
  __shared__ __align__(16) unsigned short wB[C8N * ESTR];
  __shared__ __align__(16) float h_lds[BM * HSTR];
  __shared__ float w2_lds[L_OUT * C8N];
  __shared__ float b1_lds[C8N];

  const int tid = threadIdx.x;
  const int m0 = blockIdx.x * BM;
  const int lane = tid & 63;
  const int wv = tid >> 6;
  const int l15 = lane & 15;
  const int khi = (lane >> 4) << 3;   // 0,8,16,24

  for (int i = tid; i < L_OUT * C8N; i += 256) w2_lds[i] = w2[i];
  if (tid < C8N) b1_lds[tid] = b1[tid];

  f32x4 acc[6];
  #pragma unroll
  for (int t = 0; t < 6; ++t) acc[t] = (f32x4){0.f, 0.f, 0.f, 0.f};

  for (int k0 = 0; k0 < C_IN; k0 += BK) {
    __syncthreads();
    // stage e tile: 64 rows x 32 k, f32 -> bf16
    #pragma unroll
    for (int q = 0; q < 2; ++q) {
      int f = tid + q * 256;
      int r = f >> 3, c4 = (f & 7) << 2;
      int p = m0 + r; if (p >= M_TOT) p = M_TOT - 1;
      float4 v = *(const float4*)(e + (size_t)p * C_IN + k0 + c4);
      ushort4 s; s.x = f2bf(v.x); s.y = f2bf(v.y); s.z = f2bf(v.z); s.w = f2bf(v.w);
      *(ushort4*)&eA[r * ESTR + c4] = s;
    }
    // stage w1 tile: 96 rows x 32 k
    #pragma unroll
    for (int q = 0; q < 3; ++q) {
      int f = tid + q * 256;
      int r = f >> 3, c4 = (f & 7) << 2;
      float4 v = *(const float4*)(w1 + (size_t)r * C_IN + k0 + c4);
      ushort4 s; s.x = f2bf(v.x); s.y = f2bf(v.y); s.z = f2bf(v.z); s.w = f2bf(v.w);
      *(ushort4*)&wB[r * ESTR + c4] = s;
    }
    __syncthreads();
    bf16x8 a = *(bf16x8*)&eA[(wv * 16 + l15) * ESTR + khi];
    #pragma unroll
    for (int t = 0; t < 6; ++t) {
      bf16x8 b = *(bf16x8*)&wB[(t * 16 + l15) * ESTR + khi];
      acc[t] = __builtin_amdgcn_mfma_f32_16x16x32_bf16(a, b, acc[t], 0, 0, 0);
    }
  }
  __syncthreads();
  // epilogue 1: h = relu(acc + b1) into LDS.  D: col=lane&15, row=4*(lane>>4)+reg
  #pragma unroll
  for (int t = 0; t < 6; ++t) {
    int n = t * 16 + l15;
    float bv = b1_lds[n];
    #pragma unroll
    for (int r = 0; r < 4; ++r) {
      int pl = wv * 16 + ((lane >> 4) << 2) + r;
      h_lds[pl * HSTR + n] = fmaxf(acc[t][r] + bv, 0.f);
    }
  }
  __syncthreads();
  // epilogue 2: y57[p][l] = h[p][:] . w2[l][:]  (l=21..23 pads -> 0)
  for (int i = tid; i < BM * 24; i += 256) {
    int px = i & (BM - 1), l = i >> 6;
    float s = 0.f;
    if (l < L_OUT) {
      const float* hr = &h_lds[px * HSTR];
      const float* wr = &w2_lds[l * C8N];
      #pragma unroll 8
      for (int c = 0; c < C8N; ++c) s += hr[c] * wr[c];
    }
    int p = m0 + px;
    if (p < M_TOT) y57[(size_t)p * YSTR + l] = s;
  }
}

// ---------- Kernel B1: bin bilinear weights per (mask, tap) -> W[b][64][3249] ----------
__global__ __launch_bounds__(256) void binweights_kernel(
    const int* __restrict__ labels, float* __restrict__ W)
{
  __shared__ float s_w[NMASK * MSTRIDE];
  const int tid = threadIdx.x;
  const int wc0 = blockIdx.x * COLS_PB;
  const int hr0 = blockIdx.y * ROWS_PB;
  const int b = blockIdx.z;
  for (int i = tid; i < NMASK*MSTRIDE; i += 256) s_w[i] = 0.f;
  __syncthreads();
  float thb = fminf(fmaxf((hr0 + 0.5f) * SCALE - 0.5f, 0.f), 56.f);
  const int ib = min((int)thb, 55);
  float twb = fminf(fmaxf((wc0 + 0.5f) * SCALE - 0.5f, 0.f), 56.f);
  const int jb = min((int)twb, 55);
  const int* lb = labels + (size_t)b * OUT_HW * OUT_HW;
  for (int i = tid; i < ROWS_PB*COLS_PB; i += 256) {
    int dh = i / COLS_PB;
    int dw = i - dh * COLS_PB;
    int hh = hr0 + dh, ww = wc0 + dw;
    float th = fminf(fmaxf((hh + 0.5f) * SCALE - 0.5f, 0.f), 56.f);
    int i0 = min((int)th, 55);
    float fh = th - (float)i0;
    float tw = fminf(fmaxf((ww + 0.5f) * SCALE - 0.5f, 0.f), 56.f);
    int j0 = min((int)tw, 55);
    float fw = tw - (float)j0;
    int m = lb[(size_t)hh * OUT_HW + ww] & (NMASK-1);
    float* sm = s_w + m * MSTRIDE + (i0 - ib) * COLS_T + (j0 - jb);
    float w11 = fh * fw;
    float w10 = fh - w11;
    float w01 = fw - w11;
    float w00 = 1.f - fh - fw + w11;
    unsafeAtomicAdd(sm, w00);
    unsafeAtomicAdd(sm + 1, w01);
    unsafeAtomicAdd(sm + COLS_T, w10);
    unsafeAtomicAdd(sm + COLS_T + 1, w11);
  }
  __syncthreads();
  float* Wb = W + (size_t)b * NMASK * NPIX;
  for (int i = tid; i < NMASK * ROWS_T * COLS_T; i += 256) {
    int m = i / (ROWS_T*COLS_T);
    int r = i - m * (ROWS_T*COLS_T);
    int li = r / COLS_T, lj = r - li * COLS_T;
    float v = s_w[m*MSTRIDE + r];
    int I = ib + li, J = jb + lj;
    if (v != 0.f && I <= 56 && J <= 56)
      unsafeAtomicAdd(&Wb[(size_t)m * NPIX + I*H_TOKN + J], v);
  }
}

// ---------- Kernel B2: sums[b][m][:] = W[b][m][:] @ y57[b];  counts = sum(W) ----------
__global__ __launch_bounds__(256) void segreduce_kernel(
    const float* __restrict__ W, const float* __restrict__ y57,
    float* __restrict__ sums, float* __restrict__ counts)
{
  const int bm = blockIdx.x;           // b*64 + m
  const int b = bm >> 6;
  const int tid = threadIdx.x;
  const float* wr = W + (size_t)bm * NPIX;
  const float* yb = y57 + (size_t)b * NPIX * YSTR;
  float acc[24] = {};
  float cnt = 0.f;
  for (int t = tid; t < NPIX; t += 256) {
    float wv = wr[t];
    if (wv != 0.f) {
      cnt += wv;
      const float* y = yb + (size_t)t * YSTR;
      #pragma unroll
      for (int l = 0; l < 24; l += 4) {
        float4 v = *(const float4*)(y + l);
        acc[l+0] += wv*v.x; acc[l+1] += wv*v.y;
        acc[l+2] += wv*v.z; acc[l+3] += wv*v.w;
      }
    }
  }
  #pragma unroll
  for (int off = 32; off > 0; off >>= 1) {
    #pragma unroll
    for (int l = 0; l < 24; ++l) acc[l] += __shfl_down(acc[l], off, 64);
    cnt += __shfl_down(cnt, off, 64);
  }
  __shared__ float s_red[4][28];
  const int wid = tid >> 6, lane = tid & 63;
  if (lane == 0) {
    #pragma unroll
    for (int l = 0; l < 24; ++l) s_red[wid][l] = acc[l];
    s_red[wid][24] = cnt;
  }
  __syncthreads();
  if (tid < 25) {
    float v = s_red[0][tid] + s_red[1][tid] + s_red[2][tid] + s_red[3][tid];
    if (tid < 24) sums[(size_t)bm * YSTR + tid] = v;
    else counts[bm] = v;
  }
}

// ---------- Kernel C: out[b][l][h][w] = bilinear(y57)[l] + mean[label][l] + b2[l] ----------
__global__ __launch_bounds__(256) void final_kernel(
    const float* __restrict__ y57, const int* __restrict__ labels,
    const float* __restrict__ sums, const float* __restrict__ counts,
    const float* __restrict__ b2, float* __restrict__ out)
{
  __shared__ __align__(16) float row0[H_TOKN*YSTR];
  __shared__ __align__(16) float row1[H_TOKN*YSTR];
  __shared__ __align__(16) float meanL[NMASK*28];
  const int tid = threadIdx.x;
  const int hh = blockIdx.y;
  const int b = blockIdx.z;
  float th = (hh + 0.5f) * SCALE - 0.5f;
  th = fminf(fmaxf(th, 0.f), 56.f);
  int i0 = min((int)th, 55);
  float fh = th - (float)i0;
  const float* yb = y57 + (size_t)b * NPIX * YSTR;
  const float* r0 = yb + (size_t)i0 * H_TOKN * YSTR;
  const float* r1 = r0 + H_TOKN * YSTR;
  for (int i = tid; i < H_TOKN*YSTR; i += 256) { row0[i] = r0[i]; row1[i] = r1[i]; }
  for (int i = tid; i < NMASK*YSTR; i += 256) {
    int m = i / YSTR, l = i - m * YSTR;
    meanL[m*28 + l] = sums[(size_t)b*NMASK*YSTR + i] / fmaxf(counts[b*NMASK + m], 1.f);
  }
  __syncthreads();
  float bias[L_OUT];
  #pragma unroll
  for (int l = 0; l < L_OUT; ++l) bias[l] = b2[l];
  const int* lrow = labels + ((size_t)b * OUT_HW + hh) * OUT_HW;
  float* ob = out + (size_t)b * L_OUT * OUT_HW * OUT_HW + (size_t)hh * OUT_HW;
  const float ifh = 1.f - fh;
  for (int w = tid; w < OUT_HW; w += 256) {
    float tw = (w + 0.5f) * SCALE - 0.5f;
    tw = fminf(fmaxf(tw, 0.f), 56.f);
    int j0 = min((int)tw, 55);
    float fw = tw - (float)j0;
    int m = lrow[w] & (NMASK-1);
    float w00 = ifh*(1.f-fw), w01 = ifh*fw, w10 = fh*(1.f-fw), w11 = fh*fw;
    const float4* a0 = (const float4*)&row0[j0*YSTR];
    const float4* a1 = a0 + 6;
    const float4* c0 = (const float4*)&row1[j0*YSTR];
    const float4* c1 = c0 + 6;
    const float4* mv = (const float4*)&meanL[m*28];
    #pragma unroll
    for (int c = 0; c < 6; ++c) {
      float4 A = a0[c], B = a1[c], Cc = c0[c], D = c1[c], Mv = mv[c];
      float v0 = w00*A.x + w01*B.x + w10*Cc.x + w11*D.x + Mv.x;
      float v1 = w00*A.y + w01*B.y + w10*Cc.y + w11*D.y + Mv.y;
      float v2 = w00*A.z + w01*B.z + w10*Cc.z + w11*D.z + Mv.z;
      float v3 = w00*A.w + w01*B.w + w10*Cc.w + w11*D.w + Mv.w;
      const int lb_ = c*4;
      ob[(size_t)(lb_+0)*640000 + w] = v0 + bias[lb_+0];
      if (lb_+1 < L_OUT) ob[(size_t)(lb_+1)*640000 + w] = v1 + bias[lb_+1];
      if (lb_+2 < L_OUT) ob[(size_t)(lb_+2)*640000 + w] = v2 + bias[lb_+2];
      if (lb_+3 < L_OUT) ob[(size_t)(lb_+3)*640000 + w] = v3 + bias[lb_+3];
    }
  }
}

extern "C" void kernel_launch(void* const* d_in, const int* in_sizes, int n_in,
                              void* d_out, int out_size, void* d_ws, size_t ws_size,
                              hipStream_t stream)
{
  const float* e   = (const float*)d_in[0];
  const int*   lab = (const int*)d_in[1];
  const float* w1  = (const float*)d_in[2];
  const float* b1  = (const float*)d_in[3];
  const float* w2  = (const float*)d_in[4];
  const float* b2  = (const float*)d_in[5];
  float* out = (float*)d_out;
  float* ws  = (float*)d_ws;

  float* y57_ws = ws;                                   // 6498*24 f32
  float* W_ws   = y57_ws + (size_t)M_TOT * YSTR;        // 2*64*3249 f32
  float* sums   = W_ws + (size_t)W_ELEMS;               // 2*64*24 f32
  float* cnts   = sums + 2*NMASK*YSTR;                  // 2*64 f32

  zero_w_kernel<<<dim3((W_ELEMS/4 + 255)/256), 256, 0, stream>>>(W_ws);
  fused_conv_kernel<<<dim3((M_TOT + BM - 1)/BM), 256, 0, stream>>>(e, w1, b1, w2, y57_ws);
  binweights_kernel<<<dim3(OUT_HW/COLS_PB, OUT_HW/ROWS_PB, 2), 256, 0, stream>>>(lab, W_ws);
  segreduce_kernel<<<dim3(2*NMASK), 256, 0, stream>>>(W_ws, y57_ws, sums, cnts);
  final_kernel<<<dim3(1, OUT_HW, 2), 256, 0, stream>>>(y57_ws, lab, sums, cnts, b2, out);
}